// Round 1
// baseline (916.089 us; speedup 1.0000x reference)
//
#include <hip/hip_runtime.h>
#include <hip/hip_bf16.h>

typedef short s16x8 __attribute__((ext_vector_type(8)));
typedef short s16x4 __attribute__((ext_vector_type(4)));
typedef float f32x4 __attribute__((ext_vector_type(4)));
typedef unsigned short u16;

// B=512, G=131, M = B*G = 67072, all dims 512.
#define MROWS 67072
#define GSZ   131
#define NB    512
// Vt layout: per batch, 512 rows (d) x 160 cols (k, padded), bf16
#define VT_KSTRIDE 160
#define VT_BATCH   (512 * VT_KSTRIDE)

__device__ inline u16 f2bf(float f) {               // round-half-up bf16 (cheap, ~0.5ulp)
    return (u16)((__float_as_uint(f) + 0x8000u) >> 16);
}
__device__ inline unsigned pack2(float a, float b) { // two bf16 packed in a dword
    unsigned ua = __float_as_uint(a) + 0x8000u;
    unsigned ub = __float_as_uint(b) + 0x8000u;
    return (ua >> 16) | (ub & 0xFFFF0000u);
}
__device__ inline f32x4 mfma16(s16x8 a, s16x8 b, f32x4 c) {
    return __builtin_amdgcn_mfma_f32_16x16x32_bf16(a, b, c, 0, 0, 0);
}

// ---------------------------------------------------------------------------
// NT GEMM: C[m,n] = sum_k A[m,k] * W[n,k];  M x 512 x 512, tiles 128x128xBK32.
// MODE 0: store bf16 row-major (ld 512).  MODE 1: store transposed into Vt
// layout (bf16).  MODE 2: fp32 + bias, direct store (final output).
// ABF16: A is bf16 (heads) instead of fp32.
// ---------------------------------------------------------------------------
template<int MODE, bool ABF16>
__global__ __launch_bounds__(256, 2)
void gemm_nt(const void* __restrict__ Ap, const float* __restrict__ Wp,
             void* __restrict__ Outp, const float* __restrict__ bias)
{
    extern __shared__ __align__(16) char smem[];
    u16* smA = (u16*)smem;             // 128 x 40 bf16 (pad 32->40 vs bank conflicts)
    u16* smB = (u16*)(smem + 10240);   // 128 x 40
    u16* smC = (u16*)(smem + 20480);   // 128 x 136 (modes 0/1 only)

    const int tid  = threadIdx.x;
    const int lane = tid & 63;
    const int w    = tid >> 6;
    const int wm   = w >> 1, wn = w & 1;          // 2x2 waves of 64x64
    const int mbase = (int)(blockIdx.x >> 2) * 128;
    const int nbase = (int)(blockIdx.x & 3) * 128;

    const int ra  = tid >> 1;           // staging row 0..127
    const int seg = (tid & 1) * 16;     // col segment 0/16

    const float* wsrc = Wp + (size_t)(nbase + ra) * 512 + seg;
    const float* af32 = (const float*)Ap + (size_t)(mbase + ra) * 512 + seg;
    const u16*   ab16 = (const u16*)Ap + (size_t)(mbase + ra) * 512 + seg;

    f32x4 acc[4][4];
#pragma unroll
    for (int i = 0; i < 4; ++i)
#pragma unroll
        for (int j = 0; j < 4; ++j) acc[i][j] = (f32x4){0.f, 0.f, 0.f, 0.f};

    const int lr = lane & 15;
    const int lk = (lane >> 4) * 8;

    for (int kk = 0; kk < 16; ++kk) {
        const int k0 = kk * 32;
        s16x8 av0, av1;
        if constexpr (ABF16) {
            av0 = *(const s16x8*)(ab16 + k0);
            av1 = *(const s16x8*)(ab16 + k0 + 8);
        } else {
            float4 f0 = *(const float4*)(af32 + k0);
            float4 f1 = *(const float4*)(af32 + k0 + 4);
            float4 f2 = *(const float4*)(af32 + k0 + 8);
            float4 f3 = *(const float4*)(af32 + k0 + 12);
            union { s16x8 v; unsigned u[4]; } A0, A1;
            A0.u[0] = pack2(f0.x, f0.y); A0.u[1] = pack2(f0.z, f0.w);
            A0.u[2] = pack2(f1.x, f1.y); A0.u[3] = pack2(f1.z, f1.w);
            A1.u[0] = pack2(f2.x, f2.y); A1.u[1] = pack2(f2.z, f2.w);
            A1.u[2] = pack2(f3.x, f3.y); A1.u[3] = pack2(f3.z, f3.w);
            av0 = A0.v; av1 = A1.v;
        }
        float4 g0 = *(const float4*)(wsrc + k0);
        float4 g1 = *(const float4*)(wsrc + k0 + 4);
        float4 g2 = *(const float4*)(wsrc + k0 + 8);
        float4 g3 = *(const float4*)(wsrc + k0 + 12);
        union { s16x8 v; unsigned u[4]; } B0, B1;
        B0.u[0] = pack2(g0.x, g0.y); B0.u[1] = pack2(g0.z, g0.w);
        B0.u[2] = pack2(g1.x, g1.y); B0.u[3] = pack2(g1.z, g1.w);
        B1.u[0] = pack2(g2.x, g2.y); B1.u[1] = pack2(g2.z, g2.w);
        B1.u[2] = pack2(g3.x, g3.y); B1.u[3] = pack2(g3.z, g3.w);

        *(s16x8*)&smA[ra * 40 + seg]     = av0;
        *(s16x8*)&smA[ra * 40 + seg + 8] = av1;
        *(s16x8*)&smB[ra * 40 + seg]     = B0.v;
        *(s16x8*)&smB[ra * 40 + seg + 8] = B1.v;
        __syncthreads();

        s16x8 afr[4], bfr[4];
#pragma unroll
        for (int mi = 0; mi < 4; ++mi)
            afr[mi] = *(const s16x8*)&smA[(wm * 64 + mi * 16 + lr) * 40 + lk];
#pragma unroll
        for (int ni = 0; ni < 4; ++ni)
            bfr[ni] = *(const s16x8*)&smB[(wn * 64 + ni * 16 + lr) * 40 + lk];
#pragma unroll
        for (int mi = 0; mi < 4; ++mi)
#pragma unroll
            for (int ni = 0; ni < 4; ++ni)
                acc[mi][ni] = mfma16(afr[mi], bfr[ni], acc[mi][ni]);
        __syncthreads();
    }

    // Epilogue. C/D layout: col = lane&15, row = (lane>>4)*4 + reg (m89-verified).
    if constexpr (MODE == 2) {
        float bv[4];
#pragma unroll
        for (int ni = 0; ni < 4; ++ni) bv[ni] = bias[nbase + wn * 64 + ni * 16 + lr];
        float* outp = (float*)Outp;
#pragma unroll
        for (int mi = 0; mi < 4; ++mi)
#pragma unroll
            for (int ni = 0; ni < 4; ++ni) {
                int row0 = wm * 64 + mi * 16 + (lane >> 4) * 4;
                int col  = nbase + wn * 64 + ni * 16 + lr;
#pragma unroll
                for (int r = 0; r < 4; ++r)
                    outp[(size_t)(mbase + row0 + r) * 512 + col] = acc[mi][ni][r] + bv[ni];
            }
    } else if constexpr (MODE == 0) {
#pragma unroll
        for (int mi = 0; mi < 4; ++mi)
#pragma unroll
            for (int ni = 0; ni < 4; ++ni) {
                int row0 = wm * 64 + mi * 16 + (lane >> 4) * 4;
                int col  = wn * 64 + ni * 16 + lr;
#pragma unroll
                for (int r = 0; r < 4; ++r)
                    smC[(row0 + r) * 136 + col] = f2bf(acc[mi][ni][r]);
            }
        __syncthreads();
        u16* outp = (u16*)Outp;
        int rr = tid >> 1, cs = (tid & 1) * 64;
#pragma unroll
        for (int j = 0; j < 8; ++j) {
            s16x8 v = *(const s16x8*)&smC[rr * 136 + cs + j * 8];
            *(s16x8*)(outp + (size_t)(mbase + rr) * 512 + nbase + cs + j * 8) = v;
        }
    } else { // MODE 1: transposed store into Vt[b][d][k]
#pragma unroll
        for (int mi = 0; mi < 4; ++mi)
#pragma unroll
            for (int ni = 0; ni < 4; ++ni) {
                int nl = wn * 64 + ni * 16 + lr;               // Ct row (d)
                int m0 = wm * 64 + mi * 16 + (lane >> 4) * 4;  // Ct col (m) base
                s16x4 pk;
#pragma unroll
                for (int r = 0; r < 4; ++r) pk[r] = (short)f2bf(acc[mi][ni][r]);
                *(s16x4*)&smC[nl * 136 + m0] = pk;
            }
        __syncthreads();
        u16* outp = (u16*)Outp;
        // each wave: 32 Ct rows, lanes sweep m contiguously (coalesced u16 stores)
        for (int i = 0; i < 32; ++i) {
            int n = w * 32 + i;
            int d = nbase + n;
#pragma unroll
            for (int hh = 0; hh < 2; ++hh) {
                int ml = hh * 64 + lane;
                unsigned mg = (unsigned)(mbase + ml);
                unsigned bb = mg / 131u;
                unsigned k2 = mg - bb * 131u;
                outp[(size_t)bb * VT_BATCH + (size_t)d * VT_KSTRIDE + k2] = smC[n * 136 + ml];
            }
        }
    }
}

// ---------------------------------------------------------------------------
// Attention: 1 WG = (batch b, 32-row q tile). QK^T -> softmax (fill=-30 in
// denominator, then zero masked) -> PV. Heads written bf16 over Q rows.
// ---------------------------------------------------------------------------
__global__ __launch_bounds__(256, 2)
void attn_kernel(u16* __restrict__ QHb, const u16* __restrict__ Kb,
                 const u16* __restrict__ Vtb, const int* __restrict__ mask,
                 const int* __restrict__ evp)
{
    __shared__ __align__(16) u16   Qs[32 * 520];   // Q tile (also reused for H)
    __shared__ __align__(16) float Ss[32 * 148];   // scores fp32
    __shared__ __align__(16) u16   Ps[32 * 168];   // probabilities bf16

    const int tid  = threadIdx.x;
    const int lane = tid & 63;
    const int w    = tid >> 6;
    const int blk  = blockIdx.x;
    const int b    = blk / 5;
    const int qt   = blk - b * 5;
    const int q0   = qt * 32;
    const size_t rowbase = (size_t)b * GSZ;

    // stage Q (zero-fill pad rows q>=131)
    {
        int r = tid >> 3, cs = (tid & 7) * 64;
        int q = q0 + r;
        if (q < GSZ) {
            const u16* src = QHb + (rowbase + q) * 512 + cs;
#pragma unroll
            for (int j = 0; j < 8; ++j)
                *(s16x8*)&Qs[r * 520 + cs + j * 8] = *(const s16x8*)(src + j * 8);
        } else {
            s16x8 z = (s16x8){0,0,0,0,0,0,0,0};
#pragma unroll
            for (int j = 0; j < 8; ++j) *(s16x8*)&Qs[r * 520 + cs + j * 8] = z;
        }
    }
    __syncthreads();

    const int lr = lane & 15;
    const int lk = (lane >> 4) * 8;
    const float norm = 0.044194173824159216f; // 1/sqrt(512)

    // phase 1: S = norm * Q K^T  (9 col-tiles of 16, distributed over waves)
    for (int nt = w; nt < 9; nt += 4) {
        f32x4 acc0 = (f32x4){0.f,0.f,0.f,0.f}, acc1 = acc0;
        const u16* kbase = Kb + (rowbase + nt * 16 + lr) * 512 + lk;
#pragma unroll
        for (int ks = 0; ks < 16; ++ks) {
            s16x8 bfr = *(const s16x8*)(kbase + ks * 32);
            s16x8 a0  = *(const s16x8*)&Qs[(lr) * 520 + ks * 32 + lk];
            s16x8 a1  = *(const s16x8*)&Qs[(16 + lr) * 520 + ks * 32 + lk];
            acc0 = mfma16(a0, bfr, acc0);
            acc1 = mfma16(a1, bfr, acc1);
        }
        int col = nt * 16 + lr;
        int rb  = (lane >> 4) * 4;
#pragma unroll
        for (int r = 0; r < 4; ++r) {
            Ss[(rb + r) * 148 + col]      = acc0[r] * norm;
            Ss[(16 + rb + r) * 148 + col] = acc1[r] * norm;
        }
    }
    __syncthreads();

    // softmax (8 threads per q row)
    {
        int r = tid >> 3, sub = tid & 7;
        int q = q0 + r;
        bool midq = (q >= 80) && (q < 130);
        int ev = *evp;
        float fill = ev ? -__builtin_inff() : -30.0f;
        float sv[17];
        float mx = -__builtin_inff();
#pragma unroll
        for (int j = 0; j < 17; ++j) {
            int k = sub + 8 * j;
            float s = -__builtin_inff();
            if (k < GSZ) {
                bool mk = (mask[b * GSZ + k] > 0) || (midq && (k >= 80) && (k < 130));
                s = mk ? fill : Ss[r * 148 + k];
            }
            sv[j] = s;
            mx = fmaxf(mx, s);
        }
#pragma unroll
        for (int off = 1; off < 8; off <<= 1) mx = fmaxf(mx, __shfl_xor(mx, off, 64));
        float sum = 0.f;
#pragma unroll
        for (int j = 0; j < 17; ++j) {
            int k = sub + 8 * j;
            if (k < GSZ) sum += __expf(sv[j] - mx);
        }
#pragma unroll
        for (int off = 1; off < 8; off <<= 1) sum += __shfl_xor(sum, off, 64);
        float inv = 1.0f / sum;
#pragma unroll
        for (int j = 0; j < 17; ++j) {
            int k = sub + 8 * j;
            if (k < GSZ) {
                bool mk = (mask[b * GSZ + k] > 0) || (midq && (k >= 80) && (k < 130));
                float p = mk ? 0.0f : __expf(sv[j] - mx) * inv;
                Ps[r * 168 + k] = f2bf(p);
            }
        }
        for (int k = GSZ + sub; k < 160; k += 8) Ps[r * 168 + k] = 0; // pad cols -> 0
    }
    __syncthreads();

    // phase 2: H = P * V  (wave w owns d-columns w*128..+127)
    f32x4 hacc[2][8];
#pragma unroll
    for (int mi = 0; mi < 2; ++mi)
#pragma unroll
        for (int ni = 0; ni < 8; ++ni) hacc[mi][ni] = (f32x4){0.f,0.f,0.f,0.f};
    const u16* vtbase = Vtb + (size_t)b * VT_BATCH + (size_t)(w * 128 + lr) * VT_KSTRIDE + lk;
#pragma unroll
    for (int kc = 0; kc < 5; ++kc) {
        s16x8 a0 = *(const s16x8*)&Ps[(lr) * 168 + kc * 32 + lk];
        s16x8 a1 = *(const s16x8*)&Ps[(16 + lr) * 168 + kc * 32 + lk];
#pragma unroll
        for (int ni = 0; ni < 8; ++ni) {
            s16x8 bfr = *(const s16x8*)(vtbase + (size_t)ni * 16 * VT_KSTRIDE + kc * 32);
            hacc[0][ni] = mfma16(a0, bfr, hacc[0][ni]);
            hacc[1][ni] = mfma16(a1, bfr, hacc[1][ni]);
        }
    }
    __syncthreads();

    // stage H into Qs (bf16), then coalesced store to heads (Q rows reused)
#pragma unroll
    for (int mi = 0; mi < 2; ++mi)
#pragma unroll
        for (int ni = 0; ni < 8; ++ni) {
            int row0 = mi * 16 + (lane >> 4) * 4;
            int col  = w * 128 + ni * 16 + lr;
#pragma unroll
            for (int r = 0; r < 4; ++r)
                Qs[(row0 + r) * 520 + col] = f2bf(hacc[mi][ni][r]);
        }
    __syncthreads();
    {
        int r = tid >> 3, cs = (tid & 7) * 64;
        int q = q0 + r;
        if (q < GSZ) {
            u16* dst = QHb + (rowbase + q) * 512 + cs;
#pragma unroll
            for (int j = 0; j < 8; ++j)
                *(s16x8*)(dst + j * 8) = *(const s16x8*)&Qs[r * 520 + cs + j * 8];
        }
    }
}

extern "C" void kernel_launch(void* const* d_in, const int* in_sizes, int n_in,
                              void* d_out, int out_size, void* d_ws, size_t ws_size,
                              hipStream_t stream) {
    const float* q    = (const float*)d_in[0];
    const int*   mask = (const int*)d_in[1];
    const int*   evp  = (const int*)d_in[3];
    const float* h    = (const float*)d_in[4];
    const float* Wq   = (const float*)d_in[5];
    const float* Wk   = (const float*)d_in[6];
    const float* Wv   = (const float*)d_in[7];
    const float* Wo   = (const float*)d_in[8];
    const float* bo   = (const float*)d_in[9];
    float* out = (float*)d_out;

    // ws layout (bf16): Q/heads | K | Vt  (~211 MB total)
    u16* Qbuf = (u16*)d_ws;
    u16* Kbuf = Qbuf + (size_t)MROWS * 512;
    u16* Vtb  = Kbuf + (size_t)MROWS * 512;

    dim3 gg((MROWS / 128) * 4), bb(256);
    const size_t lds_full = 55296, lds_min = 20480;

    gemm_nt<0, false><<<gg, bb, lds_full, stream>>>(q, Wq, (void*)Qbuf, nullptr);
    gemm_nt<0, false><<<gg, bb, lds_full, stream>>>(h, Wk, (void*)Kbuf, nullptr);
    gemm_nt<1, false><<<gg, bb, lds_full, stream>>>(h, Wv, (void*)Vtb, nullptr);
    attn_kernel<<<dim3(512 * 5), bb, 0, stream>>>(Qbuf, Kbuf, Vtb, mask, evp);
    gemm_nt<2, true><<<gg, bb, lds_min, stream>>>(Qbuf, Wo, (void*)out, bo);
}

// Round 2
// 728.417 us; speedup vs baseline: 1.2576x; 1.2576x over previous
//
#include <hip/hip_runtime.h>
#include <hip/hip_bf16.h>

typedef short s16x8 __attribute__((ext_vector_type(8)));
typedef short s16x4 __attribute__((ext_vector_type(4)));
typedef float f32x4 __attribute__((ext_vector_type(4)));
typedef unsigned short u16;

// B=512, G=131, M = B*G = 67072, all dims 512.
#define MROWS 67072
#define GSZ   131
// Vt layout: per batch, 512 rows (d) x 160 cols (k, padded), bf16. Lives in d_out.
#define VT_KSTRIDE 160
#define VT_BATCH   (512 * VT_KSTRIDE)

__device__ inline u16 f2bf(float f) {               // round-half-up bf16
    return (u16)((__float_as_uint(f) + 0x8000u) >> 16);
}
__device__ inline unsigned pack2(float a, float b) {
    unsigned ua = __float_as_uint(a) + 0x8000u;
    unsigned ub = __float_as_uint(b) + 0x8000u;
    return (ua >> 16) | (ub & 0xFFFF0000u);
}
__device__ inline f32x4 mfma16(s16x8 a, s16x8 b, f32x4 c) {
    return __builtin_amdgcn_mfma_f32_16x16x32_bf16(a, b, c, 0, 0, 0);
}
// async global->LDS, 16B per lane. LDS dest = wave-uniform base + lane*16.
typedef const __attribute__((address_space(1))) unsigned gas_u32;
typedef __attribute__((address_space(3))) unsigned las_u32;
__device__ inline void async16(const void* g, void* l) {
    __builtin_amdgcn_global_load_lds((gas_u32*)g, (las_u32*)l, 16, 0, 0);
}

// ---------------------------------------------------------------------------
// fp32 -> bf16 convert, 8 elems/thread, bandwidth-bound.
// ---------------------------------------------------------------------------
__global__ __launch_bounds__(256)
void cvt_kernel(const float* __restrict__ src, u16* __restrict__ dst, int n8) {
    int i = blockIdx.x * 256 + threadIdx.x;
    if (i >= n8) return;
    const float4* s4 = (const float4*)src;
    float4 a = s4[2 * (size_t)i], b = s4[2 * (size_t)i + 1];
    union { s16x8 v; unsigned u[4]; } o;
    o.u[0] = pack2(a.x, a.y); o.u[1] = pack2(a.z, a.w);
    o.u[2] = pack2(b.x, b.y); o.u[3] = pack2(b.z, b.w);
    *(s16x8*)(dst + 8 * (size_t)i) = o.v;
}

// ---------------------------------------------------------------------------
// All-bf16 NT GEMM: C[m,n] = sum_k A[m,k] * W[n,k]; M x 512 x 512.
// 128x128 tiles, BK=32, global_load_lds(16B) staging, XOR column swizzle.
// MODE 0: bf16 row-major out. MODE 1: transposed into Vt. MODE 2: fp32+bias.
// XCD swizzle: 4 n-tiles of an m-tile stay on one XCD (A rows L2-resident).
// ---------------------------------------------------------------------------
template<int MODE>
__global__ __launch_bounds__(256, 2)
void gemm_bt(const u16* __restrict__ A, const u16* __restrict__ Bw,
             void* __restrict__ Outp, const float* __restrict__ bias)
{
    extern __shared__ __align__(16) char smem[];
    u16* smA = (u16*)smem;             // 128 x 32, no pad (global_load_lds)
    u16* smB = (u16*)(smem + 8192);    // 128 x 32
    u16* smC = (u16*)smem;             // epilogue alias: 128 x 136

    const int tid  = threadIdx.x;
    const int lane = tid & 63;
    const int w    = tid >> 6;
    const int wm   = w >> 1, wn = w & 1;          // 2x2 waves of 64x64

    // XCD-aware id: grid 2096 = 8 * 262; same m-tile's 4 n-tiles share an XCD.
    const int id    = (int)(blockIdx.x & 7) * 262 + (int)(blockIdx.x >> 3);
    const int mbase = (id >> 2) * 128;
    const int nbase = (id & 3) * 128;

    // staging map: wave w, iter t in {0,1} -> LDS chunk (w*2+t)*1024B;
    // lane l -> row = w*32 + (l>>2) + 16t, col-group (global) = (l&3) ^ (row&3)
    const int srow = w * 32 + (lane >> 2);
    const int scg  = (lane & 3) ^ (srow & 3);
    const u16* agp = A  + (size_t)(mbase + srow) * 512 + scg * 8;
    const u16* bgp = Bw + (size_t)(nbase + srow) * 512 + scg * 8;
    u16* al = smA + w * 1024;
    u16* bl = smB + w * 1024;

    f32x4 acc[4][4];
#pragma unroll
    for (int i = 0; i < 4; ++i)
#pragma unroll
        for (int j = 0; j < 4; ++j) acc[i][j] = (f32x4){0.f, 0.f, 0.f, 0.f};

    const int lr = lane & 15;
    const int co = ((lane >> 4) ^ (lr & 3)) * 8;   // swizzled fragment col offset

    for (int kk = 0; kk < 16; ++kk) {
        const int k0 = kk * 32;
        async16(agp + k0,            al);
        async16(agp + k0 + 16 * 512, al + 512);
        async16(bgp + k0,            bl);
        async16(bgp + k0 + 16 * 512, bl + 512);
        __syncthreads();

        s16x8 afr[4], bfr[4];
#pragma unroll
        for (int mi = 0; mi < 4; ++mi)
            afr[mi] = *(const s16x8*)&smA[(wm * 64 + mi * 16 + lr) * 32 + co];
#pragma unroll
        for (int ni = 0; ni < 4; ++ni)
            bfr[ni] = *(const s16x8*)&smB[(wn * 64 + ni * 16 + lr) * 32 + co];
#pragma unroll
        for (int mi = 0; mi < 4; ++mi)
#pragma unroll
            for (int ni = 0; ni < 4; ++ni)
                acc[mi][ni] = mfma16(afr[mi], bfr[ni], acc[mi][ni]);
        __syncthreads();
    }

    // C/D layout: col = lane&15, row = (lane>>4)*4 + reg (m89-verified).
    if constexpr (MODE == 2) {
        float bv[4];
#pragma unroll
        for (int ni = 0; ni < 4; ++ni) bv[ni] = bias[nbase + wn * 64 + ni * 16 + lr];
        float* outp = (float*)Outp;
#pragma unroll
        for (int mi = 0; mi < 4; ++mi)
#pragma unroll
            for (int ni = 0; ni < 4; ++ni) {
                int row0 = wm * 64 + mi * 16 + (lane >> 4) * 4;
                int col  = nbase + wn * 64 + ni * 16 + lr;
#pragma unroll
                for (int r = 0; r < 4; ++r)
                    outp[(size_t)(mbase + row0 + r) * 512 + col] = acc[mi][ni][r] + bv[ni];
            }
    } else if constexpr (MODE == 0) {
#pragma unroll
        for (int mi = 0; mi < 4; ++mi)
#pragma unroll
            for (int ni = 0; ni < 4; ++ni) {
                int row0 = wm * 64 + mi * 16 + (lane >> 4) * 4;
                int col  = wn * 64 + ni * 16 + lr;
#pragma unroll
                for (int r = 0; r < 4; ++r)
                    smC[(row0 + r) * 136 + col] = f2bf(acc[mi][ni][r]);
            }
        __syncthreads();
        u16* outp = (u16*)Outp;
        int rr = tid >> 1, cs = (tid & 1) * 64;
#pragma unroll
        for (int j = 0; j < 8; ++j) {
            s16x8 v = *(const s16x8*)&smC[rr * 136 + cs + j * 8];
            *(s16x8*)(outp + (size_t)(mbase + rr) * 512 + nbase + cs + j * 8) = v;
        }
    } else { // MODE 1: transposed store into Vt[b][d][k]
#pragma unroll
        for (int mi = 0; mi < 4; ++mi)
#pragma unroll
            for (int ni = 0; ni < 4; ++ni) {
                int nl = wn * 64 + ni * 16 + lr;               // Ct row (d)
                int m0 = wm * 64 + mi * 16 + (lane >> 4) * 4;  // Ct col (m) base
                s16x4 pk;
#pragma unroll
                for (int r = 0; r < 4; ++r) pk[r] = (short)f2bf(acc[mi][ni][r]);
                *(s16x4*)&smC[nl * 136 + m0] = pk;
            }
        __syncthreads();
        u16* outp = (u16*)Outp;
        for (int i = 0; i < 32; ++i) {
            int n = w * 32 + i;
            int d = nbase + n;
#pragma unroll
            for (int hh = 0; hh < 2; ++hh) {
                int ml = hh * 64 + lane;
                unsigned mg = (unsigned)(mbase + ml);
                unsigned bb = mg / 131u;
                unsigned k2 = mg - bb * 131u;
                outp[(size_t)bb * VT_BATCH + (size_t)d * VT_KSTRIDE + k2] = smC[n * 136 + ml];
            }
        }
    }
}

// ---------------------------------------------------------------------------
// Attention: 1 WG = (batch b, 32-row q tile), XCD-swizzled so all 5 q-tiles
// of a batch share one XCD (K/Vt become L2 hits after first fetch).
// ---------------------------------------------------------------------------
__global__ __launch_bounds__(256, 2)
void attn_kernel(u16* __restrict__ QHb, const u16* __restrict__ Kb,
                 const u16* __restrict__ Vtb, const int* __restrict__ mask,
                 const int* __restrict__ evp)
{
    __shared__ __align__(16) u16   Qs[32 * 520];
    __shared__ __align__(16) float Ss[32 * 148];
    __shared__ __align__(16) u16   Ps[32 * 168];

    const int tid  = threadIdx.x;
    const int lane = tid & 63;
    const int w    = tid >> 6;
    // grid 2560 = 8 * 320; 320 % 5 == 0, so a batch never straddles XCDs.
    const int id   = (int)(blockIdx.x & 7) * 320 + (int)(blockIdx.x >> 3);
    const int b    = id / 5;
    const int qt   = id - b * 5;
    const int q0   = qt * 32;
    const size_t rowbase = (size_t)b * GSZ;

    {
        int r = tid >> 3, cs = (tid & 7) * 64;
        int q = q0 + r;
        if (q < GSZ) {
            const u16* src = QHb + (rowbase + q) * 512 + cs;
#pragma unroll
            for (int j = 0; j < 8; ++j)
                *(s16x8*)&Qs[r * 520 + cs + j * 8] = *(const s16x8*)(src + j * 8);
        } else {
            s16x8 z = (s16x8){0,0,0,0,0,0,0,0};
#pragma unroll
            for (int j = 0; j < 8; ++j) *(s16x8*)&Qs[r * 520 + cs + j * 8] = z;
        }
    }
    __syncthreads();

    const int lr = lane & 15;
    const int lk = (lane >> 4) * 8;
    const float norm = 0.044194173824159216f; // 1/sqrt(512)

    for (int nt = w; nt < 9; nt += 4) {
        f32x4 acc0 = (f32x4){0.f,0.f,0.f,0.f}, acc1 = acc0;
        const u16* kbase = Kb + (rowbase + nt * 16 + lr) * 512 + lk;
#pragma unroll
        for (int ks = 0; ks < 16; ++ks) {
            s16x8 bfr = *(const s16x8*)(kbase + ks * 32);
            s16x8 a0  = *(const s16x8*)&Qs[(lr) * 520 + ks * 32 + lk];
            s16x8 a1  = *(const s16x8*)&Qs[(16 + lr) * 520 + ks * 32 + lk];
            acc0 = mfma16(a0, bfr, acc0);
            acc1 = mfma16(a1, bfr, acc1);
        }
        int col = nt * 16 + lr;
        int rb  = (lane >> 4) * 4;
#pragma unroll
        for (int r = 0; r < 4; ++r) {
            Ss[(rb + r) * 148 + col]      = acc0[r] * norm;
            Ss[(16 + rb + r) * 148 + col] = acc1[r] * norm;
        }
    }
    __syncthreads();

    {
        int r = tid >> 3, sub = tid & 7;
        int q = q0 + r;
        bool midq = (q >= 80) && (q < 130);
        int ev = *evp;
        float fill = ev ? -__builtin_inff() : -30.0f;
        float sv[17];
        float mx = -__builtin_inff();
#pragma unroll
        for (int j = 0; j < 17; ++j) {
            int k = sub + 8 * j;
            float s = -__builtin_inff();
            if (k < GSZ) {
                bool mk = (mask[b * GSZ + k] > 0) || (midq && (k >= 80) && (k < 130));
                s = mk ? fill : Ss[r * 148 + k];
            }
            sv[j] = s;
            mx = fmaxf(mx, s);
        }
#pragma unroll
        for (int off = 1; off < 8; off <<= 1) mx = fmaxf(mx, __shfl_xor(mx, off, 64));
        float sum = 0.f;
#pragma unroll
        for (int j = 0; j < 17; ++j) {
            int k = sub + 8 * j;
            if (k < GSZ) sum += __expf(sv[j] - mx);
        }
#pragma unroll
        for (int off = 1; off < 8; off <<= 1) sum += __shfl_xor(sum, off, 64);
        float inv = 1.0f / sum;
#pragma unroll
        for (int j = 0; j < 17; ++j) {
            int k = sub + 8 * j;
            if (k < GSZ) {
                bool mk = (mask[b * GSZ + k] > 0) || (midq && (k >= 80) && (k < 130));
                float p = mk ? 0.0f : __expf(sv[j] - mx) * inv;
                Ps[r * 168 + k] = f2bf(p);
            }
        }
        for (int k = GSZ + sub; k < 160; k += 8) Ps[r * 168 + k] = 0;
    }
    __syncthreads();

    f32x4 hacc[2][8];
#pragma unroll
    for (int mi = 0; mi < 2; ++mi)
#pragma unroll
        for (int ni = 0; ni < 8; ++ni) hacc[mi][ni] = (f32x4){0.f,0.f,0.f,0.f};
    const u16* vtbase = Vtb + (size_t)b * VT_BATCH + (size_t)(w * 128 + lr) * VT_KSTRIDE + lk;
#pragma unroll
    for (int kc = 0; kc < 5; ++kc) {
        s16x8 a0 = *(const s16x8*)&Ps[(lr) * 168 + kc * 32 + lk];
        s16x8 a1 = *(const s16x8*)&Ps[(16 + lr) * 168 + kc * 32 + lk];
#pragma unroll
        for (int ni = 0; ni < 8; ++ni) {
            s16x8 bfr = *(const s16x8*)(vtbase + (size_t)ni * 16 * VT_KSTRIDE + kc * 32);
            hacc[0][ni] = mfma16(a0, bfr, hacc[0][ni]);
            hacc[1][ni] = mfma16(a1, bfr, hacc[1][ni]);
        }
    }
    __syncthreads();

#pragma unroll
    for (int mi = 0; mi < 2; ++mi)
#pragma unroll
        for (int ni = 0; ni < 8; ++ni) {
            int row0 = mi * 16 + (lane >> 4) * 4;
            int col  = w * 128 + ni * 16 + lr;
#pragma unroll
            for (int r = 0; r < 4; ++r)
                Qs[(row0 + r) * 520 + col] = f2bf(hacc[mi][ni][r]);
        }
    __syncthreads();
    {
        int r = tid >> 3, cs = (tid & 7) * 64;
        int q = q0 + r;
        if (q < GSZ) {
            u16* dst = QHb + (rowbase + q) * 512 + cs;
#pragma unroll
            for (int j = 0; j < 8; ++j)
                *(s16x8*)(dst + j * 8) = *(const s16x8*)&Qs[r * 520 + cs + j * 8];
        }
    }
}

extern "C" void kernel_launch(void* const* d_in, const int* in_sizes, int n_in,
                              void* d_out, int out_size, void* d_ws, size_t ws_size,
                              hipStream_t stream) {
    const float* q    = (const float*)d_in[0];
    const int*   mask = (const int*)d_in[1];
    const int*   evp  = (const int*)d_in[3];
    const float* h    = (const float*)d_in[4];
    const float* Wq   = (const float*)d_in[5];
    const float* Wk   = (const float*)d_in[6];
    const float* Wv   = (const float*)d_in[7];
    const float* Wo   = (const float*)d_in[8];
    const float* bo   = (const float*)d_in[9];
    float* out = (float*)d_out;

    // ws layout (u16 elems): CVT(h/q) | Kbuf | Qbuf/heads | wWq wWk wWv wWo
    // Vt (83.9 MB) lives in d_out (137 MB) and is dead before final GEMM writes.
    u16* Cbuf = (u16*)d_ws;                            // 67072*512
    u16* Kbuf = Cbuf + (size_t)MROWS * 512;
    u16* Qbuf = Kbuf + (size_t)MROWS * 512;
    u16* wWq  = Qbuf + (size_t)MROWS * 512;
    u16* wWk  = wWq + 512 * 512;
    u16* wWv  = wWk + 512 * 512;
    u16* wWo  = wWv + 512 * 512;
    u16* Vtb  = (u16*)d_out;

    const int n8_big = MROWS * 512 / 8;   // 4,292,608
    const int n8_w   = 512 * 512 / 8;     // 32,768
    dim3 bb(256);
    dim3 gcvt((n8_big + 255) / 256), gcw((n8_w + 255) / 256);
    dim3 gg(2096);
    const size_t lds_big = 34816, lds_min = 16384;

    // convert weights
    cvt_kernel<<<gcw, bb, 0, stream>>>(Wq, wWq, n8_w);
    cvt_kernel<<<gcw, bb, 0, stream>>>(Wk, wWk, n8_w);
    cvt_kernel<<<gcw, bb, 0, stream>>>(Wv, wWv, n8_w);
    cvt_kernel<<<gcw, bb, 0, stream>>>(Wo, wWo, n8_w);

    // h -> bf16; K and V projections
    cvt_kernel<<<gcvt, bb, 0, stream>>>(h, Cbuf, n8_big);
    gemm_bt<0><<<gg, bb, lds_big, stream>>>(Cbuf, wWk, (void*)Kbuf, nullptr);
    gemm_bt<1><<<gg, bb, lds_big, stream>>>(Cbuf, wWv, (void*)Vtb, nullptr);

    // q -> bf16 (reuse Cbuf); Q projection
    cvt_kernel<<<gcvt, bb, 0, stream>>>(q, Cbuf, n8_big);
    gemm_bt<0><<<gg, bb, lds_big, stream>>>(Cbuf, wWq, (void*)Qbuf, nullptr);

    attn_kernel<<<dim3(2560), bb, 0, stream>>>(Qbuf, Kbuf, Vtb, mask, evp);

    gemm_bt<2><<<gg, bb, lds_min, stream>>>(Qbuf, wWo, (void*)out, bo);
}